// Round 4
// baseline (9051.759 us; speedup 1.0000x reference)
//
#include <hip/hip_runtime.h>
#include <math.h>

// RnnModelInterp R4: 2 kernels/step; latency-optimized fp32 GEMMs.
//   S1: h1 = tanh(h0@Wih1 + Q1 + b1) ; R0 = h0@Whh0   (512 WGs x 512 thr)
//   S2: Q1' = h1@Whh1 (256 WGs) || roleB (64 WGs): heads+softmax+out+impute+h0'
// Weights packed once into [ct][k][32] contiguous tiles (WP1: Wih1|Whh0, WP2: Whh1).
// ws (floats): h0 | h1 | Q1 | R0 (256x512 each) | valc(256x64) | WP1 | WP2

#define OFF_H1 131072
#define OFF_Q1 262144
#define OFF_R0 393216
#define OFF_VALC 524288
#define OFF_WP1 540672
#define OFF_WP2 1064960
// total: 1327104 floats = 5.31 MB

__device__ __forceinline__ bool nanf_bits(float v) {
  return (__float_as_uint(v) & 0x7fffffffu) > 0x7f800000u;
}

// ---- pack: WP1[ct][k][32] (ct<16: Wih1, else Whh0); WP2[ct][k][32] (Whh1) ----
__global__ __launch_bounds__(256) void pack_weights(
    const float* __restrict__ Wih1, const float* __restrict__ Whh0,
    const float* __restrict__ Whh1, float* __restrict__ WP1,
    float* __restrict__ WP2) {
  const unsigned idx0 = blockIdx.x * 256u + threadIdx.x;
  const unsigned stride = gridDim.x * 256u;
  for (unsigned i = idx0; i < 524288u; i += stride) {
    const unsigned ct = i >> 14, rem = i & 16383u, k = rem >> 5, c = rem & 31u;
    WP1[i] = (ct < 16u) ? Wih1[k * 512u + ct * 32u + c]
                        : Whh0[k * 512u + (ct - 16u) * 32u + c];
  }
  for (unsigned i = idx0; i < 262144u; i += stride) {
    const unsigned ct = i >> 14, rem = i & 16383u, k = rem >> 5, c = rem & 31u;
    WP2[i] = Whh1[k * 512u + ct * 32u + c];
  }
}

// ---- prologue: h0 = tanh(x0@Wih0 + b0); Q1 = 0; valc = val0 ----
__global__ __launch_bounds__(512) void prologue(
    const float* __restrict__ cat_seq, const float* __restrict__ val_seq,
    const float* __restrict__ Wih0, const float* __restrict__ b0,
    float* __restrict__ h0, float* __restrict__ Q1, float* __restrict__ valc) {
  __shared__ float xs[68];
  const int w = blockIdx.x, tid = threadIdx.x;
  if (tid < 64) {
    float v = val_seq[(size_t)w * 64 + tid];
    valc[(size_t)w * 64 + tid] = v;
    xs[3 + tid] = v;
  } else if (tid < 67) {
    xs[tid - 64] = cat_seq[(size_t)w * 3 + (tid - 64)];
  }
  __syncthreads();
  float a = b0[tid];
  for (int k = 0; k < 67; ++k) a += xs[k] * Wih0[(size_t)k * 512 + tid];
  h0[(size_t)w * 512 + tid] = tanhf(a);
  Q1[(size_t)w * 512 + tid] = 0.f;
}

// Shared GEMM microkernel body: 16x32 tile, 8-way K-split, 512 threads.
// As: [16][516] staged A rows; red: [8][16][36].
__device__ __forceinline__ void gemm_tile_16x32(
    const float* __restrict__ Arows, const float* __restrict__ Wtile,
    float* __restrict__ As, float* __restrict__ red, const int tid,
    const int row0) {
  for (int idx = tid; idx < 2048; idx += 512) {
    const int r = idx >> 7, k4 = idx & 127;
    *(float4*)&As[r * 516 + k4 * 4] =
        *(const float4*)&Arows[(size_t)(row0 + r) * 512 + k4 * 4];
  }
  __syncthreads();
  const int kq = tid >> 6, pos = tid & 63;
  const int rp = pos >> 3, cq = pos & 7;
  const int r0 = rp * 2, kb = kq * 64;
  const float* Wp = Wtile + (size_t)kb * 32 + cq * 4;
  const float* A0 = &As[r0 * 516 + kb];
  const float* A1 = A0 + 516;
  float4 acc0 = {0.f, 0.f, 0.f, 0.f}, acc1 = {0.f, 0.f, 0.f, 0.f};
#pragma unroll 4
  for (int k = 0; k < 64; k += 4) {
    const float4 a0 = *(const float4*)(A0 + k);
    const float4 a1 = *(const float4*)(A1 + k);
    const float* wk = Wp + k * 32;
    const float4 w0 = *(const float4*)(wk);
    const float4 w1 = *(const float4*)(wk + 32);
    const float4 w2 = *(const float4*)(wk + 64);
    const float4 w3 = *(const float4*)(wk + 96);
    acc0.x += a0.x * w0.x + a0.y * w1.x + a0.z * w2.x + a0.w * w3.x;
    acc0.y += a0.x * w0.y + a0.y * w1.y + a0.z * w2.y + a0.w * w3.y;
    acc0.z += a0.x * w0.z + a0.y * w1.z + a0.z * w2.z + a0.w * w3.z;
    acc0.w += a0.x * w0.w + a0.y * w1.w + a0.z * w2.w + a0.w * w3.w;
    acc1.x += a1.x * w0.x + a1.y * w1.x + a1.z * w2.x + a1.w * w3.x;
    acc1.y += a1.x * w0.y + a1.y * w1.y + a1.z * w2.y + a1.w * w3.y;
    acc1.z += a1.x * w0.z + a1.y * w1.z + a1.z * w2.z + a1.w * w3.z;
    acc1.w += a1.x * w0.w + a1.y * w1.w + a1.z * w2.w + a1.w * w3.w;
  }
  float* rw = &red[(kq * 16 + r0) * 36 + cq * 4];
  *(float4*)rw = acc0;
  *(float4*)(rw + 36) = acc1;
  __syncthreads();
}

// ---- S1: bid = ct*16 + rt; ct<16 -> h1 tile, else R0 tile ----
__global__ __launch_bounds__(512) void s1_kernel(
    const float* __restrict__ h0, const float* __restrict__ Q1,
    const float* __restrict__ WP1, const float* __restrict__ b1,
    float* __restrict__ h1, float* __restrict__ R0) {
  __shared__ float smem[16 * 516 + 8 * 16 * 36];
  float* As = smem;
  float* red = smem + 16 * 516;
  const int tid = threadIdx.x;
  const int ct = blockIdx.x >> 4, rt = blockIdx.x & 15;
  const int row0 = rt * 16;
  const bool isH1 = ct < 16;
  const int cb = (isH1 ? ct : ct - 16) * 32;

  gemm_tile_16x32(h0, WP1 + (size_t)ct * 16384, As, red, tid, row0);

  const int rr = tid >> 5, cc = tid & 31;
  const float* rb = &red[rr * 36 + cc];
  float s = 0.f;
#pragma unroll
  for (int q = 0; q < 8; ++q) s += rb[q * 576];
  const int row = row0 + rr, col = cb + cc;
  if (isH1) {
    h1[(size_t)row * 512 + col] =
        tanhf(s + Q1[(size_t)row * 512 + col] + b1[col]);
  } else {
    R0[(size_t)row * 512 + col] = s;
  }
}

// ---- S2: bid<256 -> Q1' tile; bid>=256 -> roleB (4 rows each) ----
__global__ __launch_bounds__(512) void s2_kernel(
    const float* __restrict__ h1, const float* __restrict__ R0,
    const float* __restrict__ WP2, const float* __restrict__ Wih0,
    const float* __restrict__ b0, const float* __restrict__ Wc,
    const float* __restrict__ bc, const float* __restrict__ Wm,
    const float* __restrict__ bm, const float* __restrict__ cat_seq,
    const float* __restrict__ val_seq, float* __restrict__ h0,
    float* __restrict__ Q1, float* __restrict__ valc, float* __restrict__ out,
    int t) {
  __shared__ float smem[16 * 516 + 8 * 16 * 36];
  const int tid = threadIdx.x;
  if (blockIdx.x < 256) {
    float* As = smem;
    float* red = smem + 16 * 516;
    const int ct = blockIdx.x >> 4, rt = blockIdx.x & 15;
    const int row0 = rt * 16, cb = ct * 32;
    gemm_tile_16x32(h1, WP2 + (size_t)ct * 16384, As, red, tid, row0);
    const int rr = tid >> 5, cc = tid & 31;
    const float* rb = &red[rr * 36 + cc];
    float s = 0.f;
#pragma unroll
    for (int q = 0; q < 8; ++q) s += rb[q * 576];
    Q1[(size_t)(row0 + rr) * 512 + cb + cc] = s;
  } else {
    // ---- roleB: rows row0..row0+3 ----
    float* hs = smem;            // 4*516 = 2064
    float* red2 = smem + 2064;   // [8][4][64] = 2048
    float* xsr = smem + 4112;    // 4*68 = 272
    float* lg = smem + 4384;     // 12
    const int row0 = (blockIdx.x - 256) * 4;
    {
      const int r = tid >> 7, k4 = tid & 127;
      *(float4*)&hs[r * 516 + k4 * 4] =
          *(const float4*)&h1[(size_t)(row0 + r) * 512 + k4 * 4];
    }
    __syncthreads();
    {  // o_val partials: ks(8) x r(4) x qc(16)
      const int ks = tid >> 6, r = (tid >> 4) & 3, qc = tid & 15;
      const int kb = ks * 64;
      const float* hp = &hs[r * 516 + kb];
      const float* wp = Wm + (size_t)kb * 64 + qc * 4;
      float4 a = {0.f, 0.f, 0.f, 0.f};
#pragma unroll 4
      for (int k = 0; k < 64; k += 4) {
        const float4 hv = *(const float4*)(hp + k);
        const float* w = wp + (size_t)k * 64;
        const float4 w0 = *(const float4*)(w);
        const float4 w1 = *(const float4*)(w + 64);
        const float4 w2 = *(const float4*)(w + 128);
        const float4 w3 = *(const float4*)(w + 192);
        a.x += hv.x * w0.x + hv.y * w1.x + hv.z * w2.x + hv.w * w3.x;
        a.y += hv.x * w0.y + hv.y * w1.y + hv.z * w2.y + hv.w * w3.y;
        a.z += hv.x * w0.z + hv.y * w1.z + hv.z * w2.z + hv.w * w3.z;
        a.w += hv.x * w0.w + hv.y * w1.w + hv.z * w2.w + hv.w * w3.w;
      }
      *(float4*)&red2[ks * 256 + r * 64 + qc * 4] = a;
    }
    __syncthreads();
    if (tid < 256) {  // finalize o_val + impute val_next
      const int r = tid >> 6, m = tid & 63;
      float s = 0.f;
#pragma unroll
      for (int q = 0; q < 8; ++q) s += red2[q * 256 + r * 64 + m];
      const float ov = s + bm[m] + valc[(size_t)(row0 + r) * 64 + m];
      const float raw =
          val_seq[(size_t)(t + 1) * 16384 + (size_t)(row0 + r) * 64 + m];
      const float nv = nanf_bits(raw) ? ov : raw;
      valc[(size_t)(row0 + r) * 64 + m] = nv;
      xsr[r * 68 + 3 + m] = nv;
    } else {  // cat logits: waves 4..7 -> row r
      const int r = (tid >> 6) - 4, lane = tid & 63;
      float a0 = 0.f, a1 = 0.f, a2 = 0.f;
      const float* hp = &hs[r * 516 + lane * 8];
      const float* wp = Wc + (size_t)lane * 24;
#pragma unroll
      for (int kk = 0; kk < 8; ++kk) {
        const float h = hp[kk];
        a0 += h * wp[kk * 3 + 0];
        a1 += h * wp[kk * 3 + 1];
        a2 += h * wp[kk * 3 + 2];
      }
#pragma unroll
      for (int off = 32; off >= 1; off >>= 1) {
        a0 += __shfl_down(a0, off);
        a1 += __shfl_down(a1, off);
        a2 += __shfl_down(a2, off);
      }
      if (lane == 0) {
        lg[r * 3 + 0] = a0 + bc[0];
        lg[r * 3 + 1] = a1 + bc[1];
        lg[r * 3 + 2] = a2 + bc[2];
      }
    }
    __syncthreads();
    if (tid < 4) {  // softmax + out + impute cat
      const int r = tid;
      const float l0 = lg[r * 3], l1 = lg[r * 3 + 1], l2 = lg[r * 3 + 2];
      const float mx = fmaxf(l0, fmaxf(l1, l2));
      const float e0 = expf(l0 - mx), e1 = expf(l1 - mx), e2 = expf(l2 - mx);
      const float inv = 1.f / (e0 + e1 + e2);
      const float p0 = e0 * inv, p1 = e1 * inv, p2 = e2 * inv;
      const size_t ob = (size_t)t * 768 + (size_t)(row0 + r) * 3;
      out[ob] = p0; out[ob + 1] = p1; out[ob + 2] = p2;
      const size_t cbx = (size_t)(t + 1) * 768 + (size_t)(row0 + r) * 3;
      const float c0 = cat_seq[cbx], c1 = cat_seq[cbx + 1],
                  c2 = cat_seq[cbx + 2];
      xsr[r * 68 + 0] = nanf_bits(c0) ? p0 : c0;
      xsr[r * 68 + 1] = nanf_bits(c1) ? p1 : c1;
      xsr[r * 68 + 2] = nanf_bits(c2) ? p2 : c2;
    }
    __syncthreads();
    {  // h0' = tanh(x'@Wih0 + R0 + b0); one float4 per thread
      const int r = tid >> 7, c4 = (tid & 127) * 4;
      float4 acc = *(const float4*)&R0[(size_t)(row0 + r) * 512 + c4];
      const float4 bv = *(const float4*)&b0[c4];
      acc.x += bv.x; acc.y += bv.y; acc.z += bv.z; acc.w += bv.w;
      for (int k = 0; k < 67; ++k) {
        const float x = xsr[r * 68 + k];
        const float4 w = *(const float4*)&Wih0[(size_t)k * 512 + c4];
        acc.x += x * w.x; acc.y += x * w.y;
        acc.z += x * w.z; acc.w += x * w.w;
      }
      float4 o4;
      o4.x = tanhf(acc.x); o4.y = tanhf(acc.y);
      o4.z = tanhf(acc.z); o4.w = tanhf(acc.w);
      *(float4*)&h0[(size_t)(row0 + r) * 512 + c4] = o4;
    }
  }
}

extern "C" void kernel_launch(void* const* d_in, const int* in_sizes, int n_in,
                              void* d_out, int out_size, void* d_ws, size_t ws_size,
                              hipStream_t stream) {
  const float* cat_seq = (const float*)d_in[0];
  const float* val_seq = (const float*)d_in[1];
  const float* Wih0 = (const float*)d_in[2];
  const float* Whh0 = (const float*)d_in[3];
  const float* b0 = (const float*)d_in[4];
  const float* Wih1 = (const float*)d_in[5];
  const float* Whh1 = (const float*)d_in[6];
  const float* b1 = (const float*)d_in[7];
  const float* Wc = (const float*)d_in[8];
  const float* bc = (const float*)d_in[9];
  const float* Wm = (const float*)d_in[10];
  const float* bm = (const float*)d_in[11];
  float* ws = (float*)d_ws;
  float* h0 = ws;
  float* h1 = ws + OFF_H1;
  float* Q1 = ws + OFF_Q1;
  float* R0 = ws + OFF_R0;
  float* valc = ws + OFF_VALC;
  float* WP1 = ws + OFF_WP1;
  float* WP2 = ws + OFF_WP2;
  float* out = (float*)d_out;

  hipLaunchKernelGGL(pack_weights, dim3(512), dim3(256), 0, stream,
                     Wih1, Whh0, Whh1, WP1, WP2);
  hipLaunchKernelGGL(prologue, dim3(256), dim3(512), 0, stream,
                     cat_seq, val_seq, Wih0, b0, h0, Q1, valc);
  for (int t = 0; t < 199; ++t) {
    hipLaunchKernelGGL(s1_kernel, dim3(512), dim3(512), 0, stream,
                       h0, Q1, WP1, b1, h1, R0);
    hipLaunchKernelGGL(s2_kernel, dim3(320), dim3(512), 0, stream,
                       h1, R0, WP2, Wih0, b0, Wc, bc, Wm, bm,
                       cat_seq, val_seq, h0, Q1, valc, out, t);
  }
}

// Round 5
// 8672.982 us; speedup vs baseline: 1.0437x; 1.0437x over previous
//
#include <hip/hip_runtime.h>
#include <math.h>

// RnnModelInterp R5: ONE kernel dispatch per step (200 total).
// K(t) per WG (rt,ct): rows R=rt*8, cols C=ct*64.
//   reads (complete from K(t-1)): h1p=h1(t-1)[R,:], R0p[R,:], valx(t-1)[R,:]
//   S1: heads(h1p) -> softmax -> out[t-1]; impute seq[t] -> x(t)[R,:] (LDS)
//   S2: h0(t)[R,:] = tanh(x@Wih0 + R0p + b0)   (LDS only, redundant per ct)
//   S3: h1(t)[R,C] = tanh(h0@Wih1[:,C] + h1p@Whh1[:,C] + b1[C])
//       R0(t)[R,C] = h0@Whh0[:,C]
// XCD locality: ct = blockIdx.x & 7 -> each XCD owns one 64-col weight slice.
// ws (floats): h1buf[2][131072] | R0buf[2][131072] | valx[2][16384]

#define OFF_R0BUF 262144
#define OFF_VALX 524288

__device__ __forceinline__ bool nanf_bits(float v) {
  return (__float_as_uint(v) & 0x7fffffffu) > 0x7f800000u;
}

__global__ __launch_bounds__(256) void zero_init(float* __restrict__ ws) {
  const unsigned i = blockIdx.x * 256u + threadIdx.x;  // 65536 threads
  const float4 z = {0.f, 0.f, 0.f, 0.f};
  if (i < 32768u)
    *(float4*)&ws[131072u + i * 4u] = z;            // h1buf[1] = 0
  else
    *(float4*)&ws[393216u + (i - 32768u) * 4u] = z; // R0buf[1] = 0
}

__global__ __launch_bounds__(512) void rnn_step(
    const float* __restrict__ cat_seq, const float* __restrict__ val_seq,
    const float* __restrict__ Wih0, const float* __restrict__ Whh0,
    const float* __restrict__ b0, const float* __restrict__ Wih1,
    const float* __restrict__ Whh1, const float* __restrict__ b1,
    const float* __restrict__ Wc, const float* __restrict__ bc,
    const float* __restrict__ Wm, const float* __restrict__ bm,
    float* __restrict__ out, float* __restrict__ ws, int t) {
  __shared__ float h1ps[8 * 516];
  __shared__ float h0s[8 * 516];
  __shared__ float xs[8][68];
  __shared__ float red[4096];

  const int tid = threadIdx.x;
  const int ct = blockIdx.x & 7, rt = blockIdx.x >> 3;
  const int R = rt * 8, C = ct * 64;
  const int pp = (t & 1) ^ 1, pc = t & 1;
  const float* __restrict__ h1p = ws + (size_t)pp * 131072;
  float* __restrict__ h1w = ws + (size_t)pc * 131072;
  const float* __restrict__ R0p = ws + OFF_R0BUF + (size_t)pp * 131072;
  float* __restrict__ R0w = ws + OFF_R0BUF + (size_t)pc * 131072;
  const float* __restrict__ vxp = ws + OFF_VALX + (size_t)pp * 16384;
  float* __restrict__ vxw = ws + OFF_VALX + (size_t)pc * 16384;

  // ---- S1a: stage h1(t-1)[R,:] ----
  for (int idx = tid; idx < 1024; idx += 512) {
    const int r = idx >> 7, q = idx & 127;
    *(float4*)&h1ps[r * 516 + q * 4] =
        *(const float4*)&h1p[(size_t)(R + r) * 512 + q * 4];
  }
  __syncthreads();

  const int wv = tid >> 6, ln = tid & 63;  // wave = row owner, lane

  if (t > 0) {
    {  // o_val partials: ks(4) x row(8) x colquad(16)
      const int ks = tid >> 7, rr = (tid >> 4) & 7, q = tid & 15;
      const int kb = ks * 128;
      const float* hp = &h1ps[rr * 516 + kb];
      const float* wmp = Wm + (size_t)kb * 64 + q * 4;
      float ax = 0.f, ay = 0.f, az = 0.f, aw = 0.f;
#pragma unroll 4
      for (int k = 0; k < 128; ++k) {
        const float h = hp[k];
        const float4 w = *(const float4*)(wmp + (size_t)k * 64);
        ax += h * w.x; ay += h * w.y; az += h * w.z; aw += h * w.w;
      }
      float4 a = {ax, ay, az, aw};
      *(float4*)&red[ks * 512 + rr * 64 + q * 4] = a;
    }
    {  // cat head, wave-local: wave wv -> row wv
      float a0 = 0.f, a1 = 0.f, a2 = 0.f;
      const float* hp = &h1ps[wv * 516 + ln * 8];
      const float* wcp = Wc + (size_t)ln * 24;
#pragma unroll
      for (int kk = 0; kk < 8; ++kk) {
        const float h = hp[kk];
        a0 += h * wcp[kk * 3 + 0];
        a1 += h * wcp[kk * 3 + 1];
        a2 += h * wcp[kk * 3 + 2];
      }
#pragma unroll
      for (int off = 32; off >= 1; off >>= 1) {
        a0 += __shfl_down(a0, off);
        a1 += __shfl_down(a1, off);
        a2 += __shfl_down(a2, off);
      }
      if (ln == 0) {
        a0 += bc[0]; a1 += bc[1]; a2 += bc[2];
        const float mx = fmaxf(a0, fmaxf(a1, a2));
        const float e0 = expf(a0 - mx), e1 = expf(a1 - mx), e2 = expf(a2 - mx);
        const float inv = 1.f / (e0 + e1 + e2);
        const float p0 = e0 * inv, p1 = e1 * inv, p2 = e2 * inv;
        if (ct == 0) {
          const size_t ob = (size_t)(t - 1) * 768 + (size_t)(R + wv) * 3;
          out[ob] = p0; out[ob + 1] = p1; out[ob + 2] = p2;
        }
        const size_t cb = (size_t)t * 768 + (size_t)(R + wv) * 3;
        const float c0 = cat_seq[cb], c1 = cat_seq[cb + 1], c2 = cat_seq[cb + 2];
        xs[wv][0] = nanf_bits(c0) ? p0 : c0;
        xs[wv][1] = nanf_bits(c1) ? p1 : c1;
        xs[wv][2] = nanf_bits(c2) ? p2 : c2;
      }
    }
    __syncthreads();
    {  // finalize o_val, impute val -> xs, valx
      const float s = red[wv * 64 + ln] + red[512 + wv * 64 + ln] +
                      red[1024 + wv * 64 + ln] + red[1536 + wv * 64 + ln];
      const float ov = s + bm[ln] + vxp[(size_t)(R + wv) * 64 + ln];
      const float raw = val_seq[(size_t)t * 16384 + (size_t)(R + wv) * 64 + ln];
      const float nv = nanf_bits(raw) ? ov : raw;
      xs[wv][3 + ln] = nv;
      if (ct == 0) vxw[(size_t)(R + wv) * 64 + ln] = nv;
    }
  } else {
    // t == 0: x = raw seq[0] (reference uses carry0 inputs unimputed)
    const float raw = val_seq[(size_t)(R + wv) * 64 + ln];
    xs[wv][3 + ln] = raw;
    if (ct == 0) vxw[(size_t)(R + wv) * 64 + ln] = raw;
    if (ln == 0) {
      const size_t cb = (size_t)(R + wv) * 3;
      xs[wv][0] = cat_seq[cb];
      xs[wv][1] = cat_seq[cb + 1];
      xs[wv][2] = cat_seq[cb + 2];
    }
  }
  __syncthreads();

  // ---- S2: h0(t)[R,:] = tanh(x@Wih0 + R0p + b0) -> LDS (wave wv = row) ----
  {
    const int c8 = ln * 8;
    const float* r0a = &R0p[(size_t)(R + wv) * 512 + c8];
    float4 aL = *(const float4*)(r0a);
    float4 aH = *(const float4*)(r0a + 4);
    const float4 bL = *(const float4*)&b0[c8];
    const float4 bH = *(const float4*)&b0[c8 + 4];
    aL.x += bL.x; aL.y += bL.y; aL.z += bL.z; aL.w += bL.w;
    aH.x += bH.x; aH.y += bH.y; aH.z += bH.z; aH.w += bH.w;
    const float* xr = &xs[wv][0];
#pragma unroll 4
    for (int k = 0; k < 67; ++k) {
      const float x = xr[k];
      const float4 wL = *(const float4*)&Wih0[(size_t)k * 512 + c8];
      const float4 wH = *(const float4*)&Wih0[(size_t)k * 512 + c8 + 4];
      aL.x += x * wL.x; aL.y += x * wL.y; aL.z += x * wL.z; aL.w += x * wL.w;
      aH.x += x * wH.x; aH.y += x * wH.y; aH.z += x * wH.z; aH.w += x * wH.w;
    }
    float* hd = &h0s[wv * 516 + c8];
    hd[0] = tanhf(aL.x); hd[1] = tanhf(aL.y);
    hd[2] = tanhf(aL.z); hd[3] = tanhf(aL.w);
    hd[4] = tanhf(aH.x); hd[5] = tanhf(aH.y);
    hd[6] = tanhf(aH.z); hd[7] = tanhf(aH.w);
  }
  __syncthreads();

  // ---- S3: three K=512 GEMM tiles over cols C..C+63 ----
  {
    const int ks = tid >> 7, rr = (tid >> 4) & 7, q = tid & 15;
    const int kb = ks * 128;
    const float* h0a = &h0s[rr * 516 + kb];
    const float* h1a = &h1ps[rr * 516 + kb];
    const float* w1p = Wih1 + (size_t)kb * 512 + C + q * 4;
    const float* w2p = Whh1 + (size_t)kb * 512 + C + q * 4;
    const float* w3p = Whh0 + (size_t)kb * 512 + C + q * 4;
    float a1x = 0.f, a1y = 0.f, a1z = 0.f, a1w = 0.f;
    float a2x = 0.f, a2y = 0.f, a2z = 0.f, a2w = 0.f;
    float a3x = 0.f, a3y = 0.f, a3z = 0.f, a3w = 0.f;
#pragma unroll 4
    for (int k = 0; k < 128; ++k) {
      const float a = h0a[k], b = h1a[k];
      const float4 w1 = *(const float4*)(w1p + (size_t)k * 512);
      const float4 w2 = *(const float4*)(w2p + (size_t)k * 512);
      const float4 w3 = *(const float4*)(w3p + (size_t)k * 512);
      a1x += a * w1.x; a1y += a * w1.y; a1z += a * w1.z; a1w += a * w1.w;
      a2x += b * w2.x; a2y += b * w2.y; a2z += b * w2.z; a2w += b * w2.w;
      a3x += a * w3.x; a3y += a * w3.y; a3z += a * w3.z; a3w += a * w3.w;
    }
    float4 sA = {a1x + a2x, a1y + a2y, a1z + a2z, a1w + a2w};
    float4 sB = {a3x, a3y, a3z, a3w};
    *(float4*)&red[ks * 512 + rr * 64 + q * 4] = sA;
    *(float4*)&red[2048 + ks * 512 + rr * 64 + q * 4] = sB;
  }
  __syncthreads();

  // ---- S4: reduce K-splits, tanh, store (wave wv = row, lane = col) ----
  {
    const float sA = red[wv * 64 + ln] + red[512 + wv * 64 + ln] +
                     red[1024 + wv * 64 + ln] + red[1536 + wv * 64 + ln];
    const float sB = red[2048 + wv * 64 + ln] + red[2560 + wv * 64 + ln] +
                     red[3072 + wv * 64 + ln] + red[3584 + wv * 64 + ln];
    h1w[(size_t)(R + wv) * 512 + C + ln] = tanhf(sA + b1[C + ln]);
    R0w[(size_t)(R + wv) * 512 + C + ln] = sB;
  }
}

extern "C" void kernel_launch(void* const* d_in, const int* in_sizes, int n_in,
                              void* d_out, int out_size, void* d_ws, size_t ws_size,
                              hipStream_t stream) {
  const float* cat_seq = (const float*)d_in[0];
  const float* val_seq = (const float*)d_in[1];
  const float* Wih0 = (const float*)d_in[2];
  const float* Whh0 = (const float*)d_in[3];
  const float* b0 = (const float*)d_in[4];
  const float* Wih1 = (const float*)d_in[5];
  const float* Whh1 = (const float*)d_in[6];
  const float* b1 = (const float*)d_in[7];
  const float* Wc = (const float*)d_in[8];
  const float* bc = (const float*)d_in[9];
  const float* Wm = (const float*)d_in[10];
  const float* bm = (const float*)d_in[11];
  float* ws = (float*)d_ws;
  float* out = (float*)d_out;

  hipLaunchKernelGGL(zero_init, dim3(256), dim3(256), 0, stream, ws);
  for (int t = 0; t < 200; ++t) {
    hipLaunchKernelGGL(rnn_step, dim3(256), dim3(512), 0, stream,
                       cat_seq, val_seq, Wih0, Whh0, b0, Wih1, Whh1, b1,
                       Wc, bc, Wm, bm, out, ws, t);
  }
}

// Round 6
// 8374.640 us; speedup vs baseline: 1.0809x; 1.0356x over previous
//
#include <hip/hip_runtime.h>
#include <math.h>

// RnnModelInterp R6: 1 dispatch/step, latency-tolerant design.
// Grid 256 x 1024 thr (1 block/CU, 16 waves). Block (rt,ct): rows R=rt*8,
// cols C=ct*64 (ct = bid&7 -> XCD-pinned weight slices).
// Phases: stage h1p -> S1 heads+impute (k-split in-wave, shfl reduce)
//         -> S2 h0=tanh(x@Wih0+R0p+b0) (LDS only) -> S3 three K=512 GEMM
//         slices with in-wave k-split + shfl butterfly -> global writes.
// ws (floats): h1buf[2][131072] | R0buf[2][131072] | valx[2][16384]

#define OFF_R0BUF 262144
#define OFF_VALX 524288

__device__ __forceinline__ bool nanf_bits(float v) {
  return (__float_as_uint(v) & 0x7fffffffu) > 0x7f800000u;
}

__global__ __launch_bounds__(256) void zero_init(float* __restrict__ ws) {
  const unsigned i = blockIdx.x * 256u + threadIdx.x;  // 65536 threads
  const float4 z = {0.f, 0.f, 0.f, 0.f};
  if (i < 32768u)
    *(float4*)&ws[131072u + i * 4u] = z;            // h1buf[1] = 0
  else
    *(float4*)&ws[393216u + (i - 32768u) * 4u] = z; // R0buf[1] = 0
}

__global__ __launch_bounds__(1024, 4) void rnn_step(
    const float* __restrict__ cat_seq, const float* __restrict__ val_seq,
    const float* __restrict__ Wih0, const float* __restrict__ Whh0,
    const float* __restrict__ b0, const float* __restrict__ Wih1,
    const float* __restrict__ Whh1, const float* __restrict__ b1,
    const float* __restrict__ Wc, const float* __restrict__ bc,
    const float* __restrict__ Wm, const float* __restrict__ bm,
    float* __restrict__ out, float* __restrict__ ws, int t) {
  __shared__ float h1ps[8 * 516];
  __shared__ float h0s[8 * 516];
  __shared__ float xs[8][68];

  const int tid = threadIdx.x;
  const int ct = blockIdx.x & 7, rt = blockIdx.x >> 3;
  const int R = rt * 8, C = ct * 64;
  const int pp = (t & 1) ^ 1, pc = t & 1;
  const float* __restrict__ h1p = ws + (size_t)pp * 131072;
  float* __restrict__ h1w = ws + (size_t)pc * 131072;
  const float* __restrict__ R0p = ws + OFF_R0BUF + (size_t)pp * 131072;
  float* __restrict__ R0w = ws + OFF_R0BUF + (size_t)pc * 131072;
  const float* __restrict__ vxp = ws + OFF_VALX + (size_t)pp * 16384;
  float* __restrict__ vxw = ws + OFF_VALX + (size_t)pc * 16384;

  // ---- stage h1(t-1)[R..R+7, :] ----
  {
    const int r = tid >> 7, qq = tid & 127;
    *(float4*)&h1ps[r * 516 + qq * 4] =
        *(const float4*)&h1p[(size_t)(R + r) * 512 + qq * 4];
  }
  __syncthreads();

  const int wave = tid >> 6, lane = tid & 63;
  const int rr = wave >> 1, chh = wave & 1;   // row 0..7, col-half 0..1
  const int ks = lane >> 3, qq8 = lane & 7;   // k-split 0..7, col-quad 0..7

  if (t > 0) {
    // ---- S1: o_val partial for row rr, cols chh*32+qq8*4, k-slice ks ----
    float4 acc = {0.f, 0.f, 0.f, 0.f};
    {
      const int kb = ks * 64;
      const int cq = chh * 32 + qq8 * 4;
#pragma unroll 4
      for (int k4 = 0; k4 < 16; ++k4) {
        const int kk = (k4 + ks) & 15;   // rotation: de-banks LDS reads
        const int k0 = kb + kk * 4;
        const float4 hv = *(const float4*)&h1ps[rr * 516 + k0];
        const float4 w0 = *(const float4*)&Wm[(size_t)(k0 + 0) * 64 + cq];
        const float4 w1 = *(const float4*)&Wm[(size_t)(k0 + 1) * 64 + cq];
        const float4 w2 = *(const float4*)&Wm[(size_t)(k0 + 2) * 64 + cq];
        const float4 w3 = *(const float4*)&Wm[(size_t)(k0 + 3) * 64 + cq];
        acc.x += hv.x * w0.x + hv.y * w1.x + hv.z * w2.x + hv.w * w3.x;
        acc.y += hv.x * w0.y + hv.y * w1.y + hv.z * w2.y + hv.w * w3.y;
        acc.z += hv.x * w0.z + hv.y * w1.z + hv.z * w2.z + hv.w * w3.z;
        acc.w += hv.x * w0.w + hv.y * w1.w + hv.z * w2.w + hv.w * w3.w;
      }
    }
#pragma unroll
    for (int m = 8; m <= 32; m <<= 1) {   // butterfly over ks lanes
      acc.x += __shfl_xor(acc.x, m);
      acc.y += __shfl_xor(acc.y, m);
      acc.z += __shfl_xor(acc.z, m);
      acc.w += __shfl_xor(acc.w, m);
    }
    // ---- cat head on even waves (row rr) ----
    if (chh == 0) {
      float c0 = 0.f, c1 = 0.f, c2 = 0.f;
      const float* hp = &h1ps[rr * 516 + lane * 8];
      const float* wp = Wc + (size_t)lane * 24;
#pragma unroll
      for (int kk = 0; kk < 8; ++kk) {
        const float h = hp[kk];
        c0 += h * wp[kk * 3 + 0];
        c1 += h * wp[kk * 3 + 1];
        c2 += h * wp[kk * 3 + 2];
      }
#pragma unroll
      for (int off = 32; off >= 1; off >>= 1) {
        c0 += __shfl_down(c0, off);
        c1 += __shfl_down(c1, off);
        c2 += __shfl_down(c2, off);
      }
      if (lane == 0) {
        c0 += bc[0]; c1 += bc[1]; c2 += bc[2];
        const float mx = fmaxf(c0, fmaxf(c1, c2));
        const float e0 = expf(c0 - mx), e1 = expf(c1 - mx), e2 = expf(c2 - mx);
        const float inv = 1.f / (e0 + e1 + e2);
        const float p0 = e0 * inv, p1 = e1 * inv, p2 = e2 * inv;
        if (ct == 0) {
          const size_t ob = (size_t)(t - 1) * 768 + (size_t)(R + rr) * 3;
          out[ob] = p0; out[ob + 1] = p1; out[ob + 2] = p2;
        }
        const size_t cb = (size_t)t * 768 + (size_t)(R + rr) * 3;
        const float g0 = cat_seq[cb], g1 = cat_seq[cb + 1], g2 = cat_seq[cb + 2];
        xs[rr][0] = nanf_bits(g0) ? p0 : g0;
        xs[rr][1] = nanf_bits(g1) ? p1 : g1;
        xs[rr][2] = nanf_bits(g2) ? p2 : g2;
      }
    }
    // ---- finalize o_val + impute val (writers: ks==0 lanes) ----
    if (lane < 8) {
      const int cq = chh * 32 + lane * 4;
      const float4 vp = *(const float4*)&vxp[(size_t)(R + rr) * 64 + cq];
      const float4 bmv = *(const float4*)&bm[cq];
      const float4 raw = *(const float4*)&val_seq[(size_t)t * 16384 +
                                                  (size_t)(R + rr) * 64 + cq];
      float4 nv;
      nv.x = nanf_bits(raw.x) ? (acc.x + bmv.x + vp.x) : raw.x;
      nv.y = nanf_bits(raw.y) ? (acc.y + bmv.y + vp.y) : raw.y;
      nv.z = nanf_bits(raw.z) ? (acc.z + bmv.z + vp.z) : raw.z;
      nv.w = nanf_bits(raw.w) ? (acc.w + bmv.w + vp.w) : raw.w;
      xs[rr][3 + cq + 0] = nv.x;
      xs[rr][3 + cq + 1] = nv.y;
      xs[rr][3 + cq + 2] = nv.z;
      xs[rr][3 + cq + 3] = nv.w;
      if (ct == 0) *(float4*)&vxw[(size_t)(R + rr) * 64 + cq] = nv;
    }
  } else {
    // t==0: raw carry0 inputs
    if (tid < 512) {
      const int r = tid >> 6, m = tid & 63;
      const float raw = val_seq[(size_t)(R + r) * 64 + m];
      xs[r][3 + m] = raw;
      if (ct == 0) vxw[(size_t)(R + r) * 64 + m] = raw;
    } else if (tid < 520) {
      const int r = tid - 512;
      xs[r][0] = cat_seq[(size_t)(R + r) * 3 + 0];
      xs[r][1] = cat_seq[(size_t)(R + r) * 3 + 1];
      xs[r][2] = cat_seq[(size_t)(R + r) * 3 + 2];
    }
  }
  __syncthreads();
  if (t == 199) return;  // last dispatch only needed out[198]

  // ---- S2: h0 = tanh(x@Wih0 + R0p + b0) -> h0s (cols split over threads) ----
  {
    const int c = tid & 511, rh = (tid >> 9) * 4;
    const float bv = b0[c];
    float a0 = R0p[(size_t)(R + rh + 0) * 512 + c] + bv;
    float a1 = R0p[(size_t)(R + rh + 1) * 512 + c] + bv;
    float a2 = R0p[(size_t)(R + rh + 2) * 512 + c] + bv;
    float a3 = R0p[(size_t)(R + rh + 3) * 512 + c] + bv;
    const float* wk = Wih0 + c;
#pragma unroll 4
    for (int k = 0; k < 67; ++k) {
      const float w = wk[(size_t)k * 512];
      a0 += xs[rh + 0][k] * w;
      a1 += xs[rh + 1][k] * w;
      a2 += xs[rh + 2][k] * w;
      a3 += xs[rh + 3][k] * w;
    }
    h0s[(rh + 0) * 516 + c] = tanhf(a0);
    h0s[(rh + 1) * 516 + c] = tanhf(a1);
    h0s[(rh + 2) * 516 + c] = tanhf(a2);
    h0s[(rh + 3) * 516 + c] = tanhf(a3);
  }
  __syncthreads();

  // ---- S3: h1 = tanh(h0@Wih1 + h1p@Whh1 + b1); R0 = h0@Whh0 ----
  {
    const int kb = ks * 64;
    const int Cq = C + chh * 32 + qq8 * 4;
    const float* base1 = Wih1 + Cq;
    const float* base2 = Whh1 + Cq;
    const float* base3 = Whh0 + Cq;
    float4 s1v = {0.f, 0.f, 0.f, 0.f};
    float4 s2v = {0.f, 0.f, 0.f, 0.f};
    float4 s3v = {0.f, 0.f, 0.f, 0.f};
#pragma unroll 2
    for (int k4 = 0; k4 < 16; ++k4) {
      const int kk = (k4 + ks) & 15;
      const int k0 = kb + kk * 4;
      const float4 ha = *(const float4*)&h0s[rr * 516 + k0];
      const float4 hb = *(const float4*)&h1ps[rr * 516 + k0];
      {
        const float4 w1 = *(const float4*)(base1 + (size_t)(k0 + 0) * 512);
        const float4 w2 = *(const float4*)(base2 + (size_t)(k0 + 0) * 512);
        const float4 w3 = *(const float4*)(base3 + (size_t)(k0 + 0) * 512);
        s1v.x += ha.x * w1.x; s1v.y += ha.x * w1.y; s1v.z += ha.x * w1.z; s1v.w += ha.x * w1.w;
        s2v.x += hb.x * w2.x; s2v.y += hb.x * w2.y; s2v.z += hb.x * w2.z; s2v.w += hb.x * w2.w;
        s3v.x += ha.x * w3.x; s3v.y += ha.x * w3.y; s3v.z += ha.x * w3.z; s3v.w += ha.x * w3.w;
      }
      {
        const float4 w1 = *(const float4*)(base1 + (size_t)(k0 + 1) * 512);
        const float4 w2 = *(const float4*)(base2 + (size_t)(k0 + 1) * 512);
        const float4 w3 = *(const float4*)(base3 + (size_t)(k0 + 1) * 512);
        s1v.x += ha.y * w1.x; s1v.y += ha.y * w1.y; s1v.z += ha.y * w1.z; s1v.w += ha.y * w1.w;
        s2v.x += hb.y * w2.x; s2v.y += hb.y * w2.y; s2v.z += hb.y * w2.z; s2v.w += hb.y * w2.w;
        s3v.x += ha.y * w3.x; s3v.y += ha.y * w3.y; s3v.z += ha.y * w3.z; s3v.w += ha.y * w3.w;
      }
      {
        const float4 w1 = *(const float4*)(base1 + (size_t)(k0 + 2) * 512);
        const float4 w2 = *(const float4*)(base2 + (size_t)(k0 + 2) * 512);
        const float4 w3 = *(const float4*)(base3 + (size_t)(k0 + 2) * 512);
        s1v.x += ha.z * w1.x; s1v.y += ha.z * w1.y; s1v.z += ha.z * w1.z; s1v.w += ha.z * w1.w;
        s2v.x += hb.z * w2.x; s2v.y += hb.z * w2.y; s2v.z += hb.z * w2.z; s2v.w += hb.z * w2.w;
        s3v.x += ha.z * w3.x; s3v.y += ha.z * w3.y; s3v.z += ha.z * w3.z; s3v.w += ha.z * w3.w;
      }
      {
        const float4 w1 = *(const float4*)(base1 + (size_t)(k0 + 3) * 512);
        const float4 w2 = *(const float4*)(base2 + (size_t)(k0 + 3) * 512);
        const float4 w3 = *(const float4*)(base3 + (size_t)(k0 + 3) * 512);
        s1v.x += ha.w * w1.x; s1v.y += ha.w * w1.y; s1v.z += ha.w * w1.z; s1v.w += ha.w * w1.w;
        s2v.x += hb.w * w2.x; s2v.y += hb.w * w2.y; s2v.z += hb.w * w2.z; s2v.w += hb.w * w2.w;
        s3v.x += ha.w * w3.x; s3v.y += ha.w * w3.y; s3v.z += ha.w * w3.z; s3v.w += ha.w * w3.w;
      }
    }
    float4 sA = {s1v.x + s2v.x, s1v.y + s2v.y, s1v.z + s2v.z, s1v.w + s2v.w};
    float4 sB = s3v;
#pragma unroll
    for (int m = 8; m <= 32; m <<= 1) {
      sA.x += __shfl_xor(sA.x, m); sA.y += __shfl_xor(sA.y, m);
      sA.z += __shfl_xor(sA.z, m); sA.w += __shfl_xor(sA.w, m);
      sB.x += __shfl_xor(sB.x, m); sB.y += __shfl_xor(sB.y, m);
      sB.z += __shfl_xor(sB.z, m); sB.w += __shfl_xor(sB.w, m);
    }
    if (lane < 8) {
      const int col = C + chh * 32 + lane * 4;
      const float4 bv = *(const float4*)&b1[col];
      float4 ho;
      ho.x = tanhf(sA.x + bv.x);
      ho.y = tanhf(sA.y + bv.y);
      ho.z = tanhf(sA.z + bv.z);
      ho.w = tanhf(sA.w + bv.w);
      *(float4*)&h1w[(size_t)(R + rr) * 512 + col] = ho;
      *(float4*)&R0w[(size_t)(R + rr) * 512 + col] = sB;
    }
  }
}

extern "C" void kernel_launch(void* const* d_in, const int* in_sizes, int n_in,
                              void* d_out, int out_size, void* d_ws, size_t ws_size,
                              hipStream_t stream) {
  const float* cat_seq = (const float*)d_in[0];
  const float* val_seq = (const float*)d_in[1];
  const float* Wih0 = (const float*)d_in[2];
  const float* Whh0 = (const float*)d_in[3];
  const float* b0 = (const float*)d_in[4];
  const float* Wih1 = (const float*)d_in[5];
  const float* Whh1 = (const float*)d_in[6];
  const float* b1 = (const float*)d_in[7];
  const float* Wc = (const float*)d_in[8];
  const float* bc = (const float*)d_in[9];
  const float* Wm = (const float*)d_in[10];
  const float* bm = (const float*)d_in[11];
  float* ws = (float*)d_ws;
  float* out = (float*)d_out;

  hipLaunchKernelGGL(zero_init, dim3(256), dim3(256), 0, stream, ws);
  for (int t = 0; t < 200; ++t) {
    hipLaunchKernelGGL(rnn_step, dim3(256), dim3(1024), 0, stream,
                       cat_seq, val_seq, Wih0, Whh0, b0, Wih1, Whh1, b1,
                       Wc, bc, Wm, bm, out, ws, t);
  }
}